// Round 2
// baseline (5907.135 us; speedup 1.0000x reference)
//
#include <hip/hip_runtime.h>
#include <cstdint>
#include <cstddef>

// Problem constants
#define BB_ 16
#define HH_ 64
#define WW_ 64
#define CC_ 256
#define WD_ 127
#define RPD 1024   // rows per direction (B*H)
#define RT_ 2048   // total rows (both directions stacked)
#define NBLK 256u  // persistent grid size (<= 256 CUs -> co-resident)

typedef float  f32x4 __attribute__((ext_vector_type(4)));
typedef short  s16x8 __attribute__((ext_vector_type(8)));

#define MFMA16(a, b, c) __builtin_amdgcn_mfma_f32_16x16x32_bf16(a, b, c, 0, 0, 0)

__device__ __forceinline__ unsigned short f2bf(float f) {
  unsigned u = __float_as_uint(f);
  u += 0x7fffu + ((u >> 16) & 1u);   // round-to-nearest-even
  return (unsigned short)(u >> 16);
}
__device__ __forceinline__ float bf2f(unsigned short h) {
  return __uint_as_float(((unsigned)h) << 16);
}

// ---------------------------------------------------------------------------
// prep: masked i2s weights (fp32), bf16 B-operand weight packs, fused biases.
// Gate-interleaved: n = chb*64 + g*16 + cl, ch = chb*16+cl, orig row j = g*256+ch.
// ---------------------------------------------------------------------------
__global__ __launch_bounds__(256) void prep_kernel(
    const float* __restrict__ w_i2s, const float* __restrict__ b_i2s,
    const float* __restrict__ w_ih,  const float* __restrict__ b_ih,
    const float* __restrict__ b_hh,  const float* __restrict__ k0,
    const float* __restrict__ k1,    const float* __restrict__ b_s2s,
    float* __restrict__ wm, unsigned short* __restrict__ K01,
    unsigned short* __restrict__ W2T, float* __restrict__ cvec,
    float* __restrict__ gbias) {
  int idx = blockIdx.x * 256 + threadIdx.x;
  if (idx < 65536) {                       // wm[c][cin], masked
    int c = idx >> 8, ci = idx & 255;
    wm[idx] = ((ci % 3) <= (c % 3)) ? w_i2s[idx] : 0.0f;
  }
  int i2 = idx - 65536;                    // K01[n][k], k<256->k0 row n, else k1
  if (i2 >= 0 && i2 < 131072) {
    int n = i2 >> 9, k = i2 & 511;
    float v = (k < 256) ? k0[n * 256 + k] : k1[n * 256 + (k - 256)];
    K01[i2] = f2bf(v);
  }
  int i3 = idx - 196608;                   // W2T[n][k] = w_ih[j(n)][k]
  if (i3 >= 0 && i3 < 262144) {
    int n = i3 >> 8, k = i3 & 255;
    int chb = n >> 6, g = (n >> 4) & 3, cl = n & 15;
    int j = g * 256 + chb * 16 + cl;
    W2T[i3] = f2bf(w_ih[j * 256 + k]);
  }
  int i4 = idx - 458752;                   // cvec = b_i2s + b_s2s
  if (i4 >= 0 && i4 < 256) cvec[i4] = b_i2s[i4] + b_s2s[i4];
  int i5 = idx - 459008;                   // gbias[n] = b_ih[j] + b_hh[j]
  if (i5 >= 0 && i5 < 1024) {
    int chb = i5 >> 6, g = (i5 >> 4) & 3, cl = i5 & 15;
    int j = g * 256 + chb * 16 + cl;
    gbias[i5] = b_ih[j] + b_hh[j];
  }
}

// ---------------------------------------------------------------------------
// xs: banded masked 1x1 conv, once per (bb,i), reused for both directions.
// Layout xs[dir][row][j][c] bf16, j = t - i.
// ---------------------------------------------------------------------------
__global__ __launch_bounds__(256) void xs_kernel(
    const float* __restrict__ x, const float* __restrict__ wm,
    unsigned short* __restrict__ xs) {
  extern __shared__ float xt[];                   // [256 cin][64 j]
  int blk = blockIdx.x;                           // bb*64 + i
  int bb = blk >> 6, ii = blk & 63;
  int tid = threadIdx.x;
  {
    const float4* src = (const float4*)(x + (((size_t)bb * 256 + tid) * 64 + ii) * 64);
    float4* dst = (float4*)(xt + tid * 64);
#pragma unroll
    for (int q = 0; q < 16; q++) dst[q] = src[q];
  }
  __syncthreads();

  int cp = tid & 127, c0 = cp * 2;
  int j0 = (tid >> 7) * 32;                       // wave-uniform (0 or 32)
  float acc0[32], acc1[32];
#pragma unroll
  for (int q = 0; q < 32; q++) { acc0[q] = 0.f; acc1[q] = 0.f; }

  for (int c4 = 0; c4 < 64; c4++) {
    float4 wa = *(const float4*)(wm + c0 * 256 + c4 * 4);
    float4 wb = *(const float4*)(wm + (c0 + 1) * 256 + c4 * 4);
    float wav[4] = {wa.x, wa.y, wa.z, wa.w};
    float wbv[4] = {wb.x, wb.y, wb.z, wb.w};
#pragma unroll
    for (int j4 = 0; j4 < 8; j4++) {
#pragma unroll
      for (int i = 0; i < 4; i++) {
        float4 xv = *(const float4*)(xt + (c4 * 4 + i) * 64 + j0 + j4 * 4);
        acc0[j4 * 4 + 0] = fmaf(wav[i], xv.x, acc0[j4 * 4 + 0]);
        acc0[j4 * 4 + 1] = fmaf(wav[i], xv.y, acc0[j4 * 4 + 1]);
        acc0[j4 * 4 + 2] = fmaf(wav[i], xv.z, acc0[j4 * 4 + 2]);
        acc0[j4 * 4 + 3] = fmaf(wav[i], xv.w, acc0[j4 * 4 + 3]);
        acc1[j4 * 4 + 0] = fmaf(wbv[i], xv.x, acc1[j4 * 4 + 0]);
        acc1[j4 * 4 + 1] = fmaf(wbv[i], xv.y, acc1[j4 * 4 + 1]);
        acc1[j4 * 4 + 2] = fmaf(wbv[i], xv.z, acc1[j4 * 4 + 2]);
        acc1[j4 * 4 + 3] = fmaf(wbv[i], xv.w, acc1[j4 * 4 + 3]);
      }
    }
  }
  size_t row = (size_t)blk;
#pragma unroll
  for (int q = 0; q < 32; q++) {
    int j = j0 + q;
    unsigned pv = (unsigned)f2bf(acc0[q]) | ((unsigned)f2bf(acc1[q]) << 16);
    *(unsigned*)(xs + ((row * 64 + j) * 256 + c0)) = pv;                      // dir0
    *(unsigned*)(xs + (16777216u + (row * 64 + (63 - j)) * 256 + c0)) = pv;   // dir1
  }
}

// ---------------------------------------------------------------------------
// grid barrier: sense-reversal, agent-scope atomics (coherent point is
// memory-side on multi-XCD gfx950; release arrive = L2 writeback, acquire
// exit = L2 invalidate — emitted by the compiler's gfx95x memory model).
// ---------------------------------------------------------------------------
__device__ __forceinline__ void gsync(unsigned* bar, unsigned* gen) {
  __syncthreads();
  if (threadIdx.x == 0) {
    unsigned g = __hip_atomic_load(gen, __ATOMIC_RELAXED, __HIP_MEMORY_SCOPE_AGENT);
    unsigned arr = __hip_atomic_fetch_add(bar, 1u, __ATOMIC_ACQ_REL,
                                          __HIP_MEMORY_SCOPE_AGENT);
    if (arr == NBLK - 1u) {
      __hip_atomic_store(bar, 0u, __ATOMIC_RELAXED, __HIP_MEMORY_SCOPE_AGENT);
      __hip_atomic_fetch_add(gen, 1u, __ATOMIC_RELEASE, __HIP_MEMORY_SCOPE_AGENT);
    } else {
      while (__hip_atomic_load(gen, __ATOMIC_RELAXED, __HIP_MEMORY_SCOPE_AGENT) == g)
        __builtin_amdgcn_s_sleep(2);
      __builtin_amdgcn_fence(__ATOMIC_ACQUIRE, "agent");
    }
  }
  __syncthreads();
}

// ---------------------------------------------------------------------------
// persistent LSTM: all 127 steps in one kernel, 2 grid syncs per step.
// Block roles: A: 32 M-tiles(64) x 8 N-tiles(32); B: same M x 8 N-tiles(128).
// K01 wave-slice in registers; W2T block-slice in LDS (xor-swizzled granules);
// c-state in registers (same wave owns same (R,ch) every step).
// ---------------------------------------------------------------------------
__global__ __launch_bounds__(256, 2) void lstm_persist(
    const unsigned short* __restrict__ K01,
    const unsigned short* __restrict__ W2T,
    const unsigned short* __restrict__ xs,
    const float* __restrict__ cvec, const float* __restrict__ gbias,
    unsigned short* __restrict__ tmp, unsigned short* __restrict__ hs,
    unsigned* __restrict__ bar) {
  __shared__ uint4 ldsW[4096];   // 64 KiB: [c(128)][g(32)] 16B granules, swizzled
  int blk = blockIdx.x;
  int tid = threadIdx.x, lane = tid & 63, w = tid >> 6;
  int l15 = lane & 15, l4 = lane >> 4;
  int r0 = (blk >> 3) * 64;
  int rbase = r0 + (w >> 1) * 32;
  int n0b = (blk & 7) * 128;

  { // stage W2T slice -> LDS, xor swizzle granule g by (c&31)
    const uint4* src = (const uint4*)(W2T + n0b * 256);
    for (int i = tid; i < 4096; i += 256) {
      int c = i >> 5, g = i & 31;
      ldsW[c * 32 + (g ^ (c & 31))] = src[i];
    }
  }
  // phase-A weight frags, register-resident (16 frags = 64 VGPRs)
  int nbA = (blk & 7) * 32 + (w & 1) * 16;
  s16x8 bA[16];
  {
    const unsigned short* pb = K01 + (nbA + l15) * 512 + l4 * 8;
#pragma unroll
    for (int ks = 0; ks < 16; ks++) bA[ks] = *(const s16x8*)(pb + ks * 32);
  }
  // constant addressing
  int R0 = rbase + l15, R1 = rbase + 16 + l15;
  bool m0 = ((R0 & 1023) == 1023), m1 = ((R1 & 1023) == 1023);
  const unsigned short* paT0 = tmp + R0 * 256 + l4 * 8;   // phase-B A-frags
  const unsigned short* paT1 = tmp + R1 * 256 + l4 * 8;
  int CcolA = nbA + l15;
  float cv = cvec[CcolA];
  int nbase = n0b + (w & 1) * 64;
  int ch = (nbase >> 2) + l15;
  float gb0 = gbias[nbase + l15], gb1 = gbias[nbase + 16 + l15];
  float gb2 = gbias[nbase + 32 + l15], gb3 = gbias[nbase + 48 + l15];
  // per-output-element precomputed offsets (mi*4+r)
  int wofA[8], hoff[8], iis[8];
  const unsigned short* xsp[8];
#pragma unroll
  for (int k = 0; k < 8; k++) {
    int mi = k >> 2, r = k & 3;
    int R = rbase + mi * 16 + l4 * 4 + r;
    int rl = R & 1023, dir = R >> 10;
    wofA[k] = R * 256 + CcolA;
    hoff[k] = R * 256 + ch;
    iis[k] = rl & 63;
    xsp[k] = xs + (size_t)dir * 16777216u + (size_t)rl * 64 * 256 + CcolA;
  }
  float cr[8] = {0.f, 0.f, 0.f, 0.f, 0.f, 0.f, 0.f, 0.f};
  const s16x8 z = {0, 0, 0, 0, 0, 0, 0, 0};
  unsigned* genp = bar + 16;   // separate cache lines
  __syncthreads();             // LDS staged

  for (int t = 0; t < 127; t++) {
    // ---------------- phase A: tmp = hprev@k0T + hnext@k1T + xs + cvec ------
    f32x4 acc0 = {0.f, 0.f, 0.f, 0.f}, acc1 = {0.f, 0.f, 0.f, 0.f};
    if (t > 0) {
      const unsigned short* hp = hs + (size_t)(t - 1) * (RT_ * CC_);
      const unsigned short* pa0 = hp + R0 * 256 + l4 * 8;
      const unsigned short* pa1 = hp + R1 * 256 + l4 * 8;
#pragma unroll
      for (int ks = 0; ks < 8; ks++) {          // k0: h_prev
        s16x8 a0 = *(const s16x8*)(pa0 + ks * 32);
        s16x8 a1 = *(const s16x8*)(pa1 + ks * 32);
        acc0 = MFMA16(a0, bA[ks], acc0);
        acc1 = MFMA16(a1, bA[ks], acc1);
      }
#pragma unroll
      for (int ks = 0; ks < 8; ks++) {          // k1: h_next (= row+1)
        s16x8 a0 = m0 ? z : *(const s16x8*)(pa0 + 256 + ks * 32);
        s16x8 a1 = m1 ? z : *(const s16x8*)(pa1 + 256 + ks * 32);
        acc0 = MFMA16(a0, bA[8 + ks], acc0);
        acc1 = MFMA16(a1, bA[8 + ks], acc1);
      }
    }
#pragma unroll
    for (int k = 0; k < 8; k++) {
      float v = (k < 4 ? acc0[k & 3] : acc1[k & 3]) + cv;
      int j = t - iis[k];
      if (j >= 0 && j < 64) v += bf2f(xsp[k][j * 256]);
      tmp[wofA[k]] = f2bf(v);
    }
    gsync(bar, genp);
    // ---------------- phase B: gates = tmp@W2T + LSTM ----------------------
    f32x4 acc[2][4];
#pragma unroll
    for (int a = 0; a < 2; a++)
#pragma unroll
      for (int b = 0; b < 4; b++) acc[a][b] = (f32x4){0.f, 0.f, 0.f, 0.f};
#pragma unroll
    for (int ks = 0; ks < 8; ks++) {
      s16x8 a0 = *(const s16x8*)(paT0 + ks * 32);
      s16x8 a1 = *(const s16x8*)(paT1 + ks * 32);
      int g = ks * 4 + l4;
#pragma unroll
      for (int ni = 0; ni < 4; ni++) {
        int c = (w & 1) * 64 + ni * 16 + l15;
        s16x8 b = *(const s16x8*)&ldsW[c * 32 + (g ^ (c & 31))];
        acc[0][ni] = MFMA16(a0, b, acc[0][ni]);
        acc[1][ni] = MFMA16(a1, b, acc[1][ni]);
      }
    }
    unsigned short* hout = hs + (size_t)t * (RT_ * CC_);
#pragma unroll
    for (int k = 0; k < 8; k++) {
      int mi = k >> 2, r = k & 3;
      float xi = acc[mi][0][r] + gb0;
      float xf = acc[mi][1][r] + gb1;
      float xg = acc[mi][2][r] + gb2;
      float xo = acc[mi][3][r] + gb3;
      float si = 1.f / (1.f + __expf(-xi));
      float sf = 1.f / (1.f + __expf(-xf));
      float so = 1.f / (1.f + __expf(-xo));
      float tg = 1.f - 2.f / (__expf(2.f * xg) + 1.f);
      float cn = sf * cr[k] + si * tg;
      cr[k] = cn;
      float th = 1.f - 2.f / (__expf(2.f * cn) + 1.f);
      hout[hoff[k]] = f2bf(so * th);
    }
    gsync(bar, genp);
  }
}

// ---------------------------------------------------------------------------
// gather: out[b,o,hh,j] = hs0[hh+j][row][c0+hh] + (hh>0)*hs1[hh-1+63-j][row][c0+hh-1]
// ---------------------------------------------------------------------------
__global__ __launch_bounds__(256) void gather_kernel(
    const unsigned short* __restrict__ hs, float* __restrict__ out) {
  __shared__ unsigned short slab0[127 * 66 + 2];
  __shared__ unsigned short slab1[127 * 66 + 2];
  int blk = blockIdx.x;                    // bb*256 + o
  int bb = blk >> 8, o = blk & 255;
  int row = bb * 64 + (o >> 2);
  int c0 = (o & 3) * 64;
  int tid = threadIdx.x;
  for (int idx = tid; idx < 127 * 32; idx += 256) {
    int tt = idx >> 5, cu = idx & 31;
    unsigned v0 = *(const unsigned*)(hs + ((size_t)tt * RT_ + row) * 256 + c0 + cu * 2);
    unsigned v1 = *(const unsigned*)(hs + ((size_t)tt * RT_ + 1024 + row) * 256 + c0 + cu * 2);
    *(unsigned*)(slab0 + tt * 66 + cu * 2) = v0;
    *(unsigned*)(slab1 + tt * 66 + cu * 2) = v1;
  }
  __syncthreads();
  int j = tid & 63;
  int hh0 = (tid >> 6) * 16;
  float* ob = out + (size_t)blk * 4096;
  for (int hh = hh0; hh < hh0 + 16; hh++) {
    float v = bf2f(slab0[(hh + j) * 66 + hh]);
    if (hh > 0) v += bf2f(slab1[(hh - 1 + 63 - j) * 66 + (hh - 1)]);
    ob[hh * 64 + j] = v;
  }
}

// ---------------------------------------------------------------------------
extern "C" void kernel_launch(void* const* d_in, const int* in_sizes, int n_in,
                              void* d_out, int out_size, void* d_ws, size_t ws_size,
                              hipStream_t stream) {
  const float* x     = (const float*)d_in[0];
  const float* w_i2s = (const float*)d_in[1];
  const float* b_i2s = (const float*)d_in[2];
  const float* w_ih  = (const float*)d_in[3];
  const float* b_ih  = (const float*)d_in[4];
  const float* b_hh  = (const float*)d_in[5];
  const float* k0    = (const float*)d_in[6];
  const float* k1    = (const float*)d_in[7];
  const float* b_s2s = (const float*)d_in[8];
  float* out = (float*)d_out;

  char* ws = (char*)d_ws;
  // workspace map (bytes)
  float*          wm     = (float*)(ws + 0);                 //   256 KiB
  float*          cvec   = (float*)(ws + 262144);            //     1 KiB
  float*          gbias  = (float*)(ws + 263168);            //     4 KiB
  unsigned short* K01    = (unsigned short*)(ws + 267264);   //   256 KiB
  unsigned short* W2T    = (unsigned short*)(ws + 529408);   //   512 KiB
  unsigned short* tmp    = (unsigned short*)(ws + 1053696);  //     1 MiB
  unsigned*       bar    = (unsigned*)(ws + 2102272);        //   128 B (barrier)
  unsigned short* xs     = (unsigned short*)(ws + 4199424);  //    64 MiB
  unsigned short* hs     = (unsigned short*)(ws + 71308288); //   127 MiB
  const size_t NEEDED = 204477440;
  if (ws_size < NEEDED) return;

  hipMemsetAsync(bar, 0, 128, stream);   // zero barrier state (ws is poisoned)
  prep_kernel<<<1797, 256, 0, stream>>>(w_i2s, b_i2s, w_ih, b_ih, b_hh, k0, k1,
                                        b_s2s, wm, K01, W2T, cvec, gbias);
  xs_kernel<<<1024, 256, 65536, stream>>>(x, wm, xs);
  lstm_persist<<<256, 256, 0, stream>>>(K01, W2T, xs, cvec, gbias, tmp, hs, bar);
  gather_kernel<<<4096, 256, 0, stream>>>(hs, out);
}

// Round 3
// 4759.888 us; speedup vs baseline: 1.2410x; 1.2410x over previous
//
#include <hip/hip_runtime.h>
#include <cstdint>
#include <cstddef>

// Problem constants
#define BB_ 16
#define HH_ 64
#define WW_ 64
#define CC_ 256
#define WD_ 127
#define RT_ 2048   // total rows (2 dirs x 1024)
#define LS_ 264    // LDS row stride in bf16 elements (528 B, 16B-aligned, conflict-free b128)

typedef float  f32x4 __attribute__((ext_vector_type(4)));
typedef short  s16x8 __attribute__((ext_vector_type(8)));

#define MFMA16(a, b, c) __builtin_amdgcn_mfma_f32_16x16x32_bf16(a, b, c, 0, 0, 0)

__device__ __forceinline__ unsigned short f2bf(float f) {
  unsigned u = __float_as_uint(f);
  u += 0x7fffu + ((u >> 16) & 1u);   // round-to-nearest-even
  return (unsigned short)(u >> 16);
}
__device__ __forceinline__ float bf2f(unsigned short h) {
  return __uint_as_float(((unsigned)h) << 16);
}

// ---------------------------------------------------------------------------
// prep: masked i2s weights (fp32), bf16 B-operand weight packs, fused biases.
// Gate-interleaved: n = chb*64 + g*16 + cl, ch = chb*16+cl, orig row j = g*256+ch.
// ---------------------------------------------------------------------------
__global__ __launch_bounds__(256) void prep_kernel(
    const float* __restrict__ w_i2s, const float* __restrict__ b_i2s,
    const float* __restrict__ w_ih,  const float* __restrict__ b_ih,
    const float* __restrict__ b_hh,  const float* __restrict__ k0,
    const float* __restrict__ k1,    const float* __restrict__ b_s2s,
    float* __restrict__ wm, unsigned short* __restrict__ K01,
    unsigned short* __restrict__ W2T, float* __restrict__ cvec,
    float* __restrict__ gbias) {
  int idx = blockIdx.x * 256 + threadIdx.x;
  if (idx < 65536) {                       // wm[c][cin], masked
    int c = idx >> 8, ci = idx & 255;
    wm[idx] = ((ci % 3) <= (c % 3)) ? w_i2s[idx] : 0.0f;
  }
  int i2 = idx - 65536;                    // K01[n][k], k<256->k0 row n, else k1
  if (i2 >= 0 && i2 < 131072) {
    int n = i2 >> 9, k = i2 & 511;
    float v = (k < 256) ? k0[n * 256 + k] : k1[n * 256 + (k - 256)];
    K01[i2] = f2bf(v);
  }
  int i3 = idx - 196608;                   // W2T[n][k] = w_ih[j(n)][k]
  if (i3 >= 0 && i3 < 262144) {
    int n = i3 >> 8, k = i3 & 255;
    int chb = n >> 6, g = (n >> 4) & 3, cl = n & 15;
    int j = g * 256 + chb * 16 + cl;
    W2T[i3] = f2bf(w_ih[j * 256 + k]);
  }
  int i4 = idx - 458752;                   // cvec = b_i2s + b_s2s
  if (i4 >= 0 && i4 < 256) cvec[i4] = b_i2s[i4] + b_s2s[i4];
  int i5 = idx - 459008;                   // gbias[n] = b_ih[j] + b_hh[j]
  if (i5 >= 0 && i5 < 1024) {
    int chb = i5 >> 6, g = (i5 >> 4) & 3, cl = i5 & 15;
    int j = g * 256 + chb * 16 + cl;
    gbias[i5] = b_ih[j] + b_hh[j];
  }
}

// ---------------------------------------------------------------------------
// xs: banded masked 1x1 conv, stored ONCE (dir1 reads mirrored j = 63-j).
// Layout xs[row(1024)][j(64)][c(256)] bf16.
// ---------------------------------------------------------------------------
__global__ __launch_bounds__(256) void xs_kernel(
    const float* __restrict__ x, const float* __restrict__ wm,
    unsigned short* __restrict__ xs) {
  extern __shared__ float xt[];                   // [256 cin][64 j]
  int blk = blockIdx.x;                           // bb*64 + i
  int bb = blk >> 6, ii = blk & 63;
  int tid = threadIdx.x;
  {
    const float4* src = (const float4*)(x + (((size_t)bb * 256 + tid) * 64 + ii) * 64);
    float4* dst = (float4*)(xt + tid * 64);
#pragma unroll
    for (int q = 0; q < 16; q++) dst[q] = src[q];
  }
  __syncthreads();

  int cp = tid & 127, c0 = cp * 2;
  int j0 = (tid >> 7) * 32;                       // wave-uniform (0 or 32)
  float acc0[32], acc1[32];
#pragma unroll
  for (int q = 0; q < 32; q++) { acc0[q] = 0.f; acc1[q] = 0.f; }

  for (int c4 = 0; c4 < 64; c4++) {
    float4 wa = *(const float4*)(wm + c0 * 256 + c4 * 4);
    float4 wb = *(const float4*)(wm + (c0 + 1) * 256 + c4 * 4);
    float wav[4] = {wa.x, wa.y, wa.z, wa.w};
    float wbv[4] = {wb.x, wb.y, wb.z, wb.w};
#pragma unroll
    for (int j4 = 0; j4 < 8; j4++) {
#pragma unroll
      for (int i = 0; i < 4; i++) {
        float4 xv = *(const float4*)(xt + (c4 * 4 + i) * 64 + j0 + j4 * 4);
        acc0[j4 * 4 + 0] = fmaf(wav[i], xv.x, acc0[j4 * 4 + 0]);
        acc0[j4 * 4 + 1] = fmaf(wav[i], xv.y, acc0[j4 * 4 + 1]);
        acc0[j4 * 4 + 2] = fmaf(wav[i], xv.z, acc0[j4 * 4 + 2]);
        acc0[j4 * 4 + 3] = fmaf(wav[i], xv.w, acc0[j4 * 4 + 3]);
        acc1[j4 * 4 + 0] = fmaf(wbv[i], xv.x, acc1[j4 * 4 + 0]);
        acc1[j4 * 4 + 1] = fmaf(wbv[i], xv.y, acc1[j4 * 4 + 1]);
        acc1[j4 * 4 + 2] = fmaf(wbv[i], xv.z, acc1[j4 * 4 + 2]);
        acc1[j4 * 4 + 3] = fmaf(wbv[i], xv.w, acc1[j4 * 4 + 3]);
      }
    }
  }
  size_t row = (size_t)blk;
#pragma unroll
  for (int q = 0; q < 32; q++) {
    int j = j0 + q;
    unsigned pv = (unsigned)f2bf(acc0[q]) | ((unsigned)f2bf(acc1[q]) << 16);
    *(unsigned*)(xs + ((row * 64 + j) * 256 + c0)) = pv;
  }
}

// ---------------------------------------------------------------------------
// persistent LSTM: 64 blocks x 32 rows, 512 threads (8 waves). All state in
// LDS; only cross-block traffic = one h row/step via relaxed agent-scope
// atomics (L2-bypass mailbox) — NO fences, NO grid barrier, NO L2 flushes.
// ---------------------------------------------------------------------------
__global__ __launch_bounds__(512, 2) void lstm_persist(
    const unsigned short* __restrict__ K01,
    const unsigned short* __restrict__ W2T,
    const unsigned short* __restrict__ xs,
    const float* __restrict__ cvec, const float* __restrict__ gbias,
    unsigned short* __restrict__ hs, unsigned* __restrict__ mbox,
    unsigned* __restrict__ flags) {
  __shared__ unsigned short hbuf[33 * LS_];   // rows 0..31 = h, row 32 = neighbor/zero
  __shared__ unsigned short tbuf[32 * LS_];   // tmpA (phase A output)

  int blk = blockIdx.x;              // tile: rows [32*blk, 32*blk+32)
  int tid = threadIdx.x, lane = tid & 63, w = tid >> 6;
  int l15 = lane & 15, l4 = lane >> 4;
  bool notLast  = ((blk & 31) != 31);   // has an upstream neighbor (reads mbox[blk])
  bool doPost   = ((blk & 31) != 0);    // posts to mbox[blk-1]

  // zero h (incl. row 32, which stays zero forever for last-of-dir tiles)
  for (int i = tid; i < (33 * LS_) / 2; i += 512) ((unsigned*)hbuf)[i] = 0u;

  // ---- wave-constant addressing ----
  int nA = 32 * w;                          // phase-A N-slice
  const unsigned short* pbA = K01 + (size_t)(nA + l15) * 512 + l4 * 8;
  const unsigned short* pbB = W2T + (size_t)(128 * w + l15) * 256 + l4 * 8;
  float cv0 = cvec[nA + l15], cv1 = cvec[nA + 16 + l15];
  float gb[2][4];
#pragma unroll
  for (int cc = 0; cc < 2; cc++)
#pragma unroll
    for (int g = 0; g < 4; g++) gb[cc][g] = gbias[128 * w + 16 * (cc * 4 + g) + l15];
  int ch0 = 32 * w + l15;                   // phase-B channels (cc=0), +16 for cc=1

  // per-output-element xs walking pointers (8 row-elems: mt*4 + r)
  const unsigned short* xp[8];
  int xd[8], xii[8];
#pragma unroll
  for (int e = 0; e < 8; e++) {
    int mt = e >> 2, r = e & 3;
    int rloc = mt * 16 + l4 * 4 + r;
    int RG = 32 * blk + rloc;
    int rl = RG & 1023, dir = RG >> 10;
    int i = rl & 63;
    xii[e] = i;
    xd[e] = dir ? -256 : 256;
    // at step t, element = xp[e] + t*xd[e]  (valid iff 0 <= t-i < 64)
    xp[e] = xs + (size_t)rl * 64 * 256 + (dir ? (63 + i) : (-i)) * 256 + nA + l15;
  }
  // h/hs epilogue offsets
  int hlds[8];   // hbuf offset for (row, ch0)
  size_t hglb[8];
#pragma unroll
  for (int e = 0; e < 8; e++) {
    int mt = e >> 2, r = e & 3;
    int rloc = mt * 16 + l4 * 4 + r;
    hlds[e] = rloc * LS_ + ch0;
    hglb[e] = (size_t)(32 * blk + rloc) * 256 + ch0;
  }

  float cr[16];
#pragma unroll
  for (int q = 0; q < 16; q++) cr[q] = 0.f;

  unsigned* myflag = flags + blk * 32;
  unsigned* upflag = flags + (blk - 1) * 32;
  __syncthreads();

  for (int t = 0; t < WD_; t++) {
    // ============ phase A: tmpA = h@k0T + hshift@k1T + xs_t + cvec =========
    f32x4 accA[2][2];
#pragma unroll
    for (int a = 0; a < 2; a++)
#pragma unroll
      for (int b = 0; b < 2; b++) accA[a][b] = (f32x4){0.f, 0.f, 0.f, 0.f};

    // k0 half: own rows (at t=0 hbuf is zero -> contributes 0, harmless)
#pragma unroll
    for (int ks = 0; ks < 8; ks++) {
      s16x8 a0 = *(const s16x8*)&hbuf[l15 * LS_ + ks * 32 + l4 * 8];
      s16x8 a1 = *(const s16x8*)&hbuf[(16 + l15) * LS_ + ks * 32 + l4 * 8];
      s16x8 b0 = *(const s16x8*)(pbA + ks * 32);
      s16x8 b1 = *(const s16x8*)(pbA + 8192 + ks * 32);
      accA[0][0] = MFMA16(a0, b0, accA[0][0]);
      accA[1][0] = MFMA16(a1, b0, accA[1][0]);
      accA[0][1] = MFMA16(a0, b1, accA[0][1]);
      accA[1][1] = MFMA16(a1, b1, accA[1][1]);
    }
    // stage neighbor row (h[t-1] row of next tile) into hbuf row 32
    if (t > 0 && notLast) {
      if (tid == 0) {
        while (__hip_atomic_load(myflag, __ATOMIC_RELAXED,
                                 __HIP_MEMORY_SCOPE_AGENT) < (unsigned)t)
          __builtin_amdgcn_s_sleep(1);
      }
      __syncthreads();
      if (tid < 128) {
        unsigned v = __hip_atomic_load(
            mbox + ((size_t)blk * WD_ + (t - 1)) * 128 + tid,
            __ATOMIC_RELAXED, __HIP_MEMORY_SCOPE_AGENT);
        ((unsigned*)(hbuf + 32 * LS_))[tid] = v;
      }
      __syncthreads();
    }
    // k1 half: shifted rows (row 32 = neighbor or zero)
#pragma unroll
    for (int ks = 0; ks < 8; ks++) {
      s16x8 a0 = *(const s16x8*)&hbuf[(1 + l15) * LS_ + ks * 32 + l4 * 8];
      s16x8 a1 = *(const s16x8*)&hbuf[(17 + l15) * LS_ + ks * 32 + l4 * 8];
      s16x8 b0 = *(const s16x8*)(pbA + 256 + ks * 32);
      s16x8 b1 = *(const s16x8*)(pbA + 8192 + 256 + ks * 32);
      accA[0][0] = MFMA16(a0, b0, accA[0][0]);
      accA[1][0] = MFMA16(a1, b0, accA[1][0]);
      accA[0][1] = MFMA16(a0, b1, accA[0][1]);
      accA[1][1] = MFMA16(a1, b1, accA[1][1]);
    }
    // epilogue A: + cvec + xs band, write tmpA (bf16) to LDS
#pragma unroll
    for (int e = 0; e < 8; e++) {
      int mt = e >> 2, r = e & 3;
      int rloc = mt * 16 + l4 * 4 + r;
      int jv = t - xii[e];
      float v0 = accA[mt][0][r] + cv0;
      float v1 = accA[mt][1][r] + cv1;
      if (jv >= 0 && jv < 64) {
        const unsigned short* p = xp[e] + (ptrdiff_t)t * xd[e];
        v0 += bf2f(p[0]);
        v1 += bf2f(p[16]);
      }
      tbuf[rloc * LS_ + nA + l15] = f2bf(v0);
      tbuf[rloc * LS_ + nA + 16 + l15] = f2bf(v1);
    }
    __syncthreads();
    // ============ phase B: gates = tmpA @ W2T, fused LSTM ==================
    f32x4 accB[2][8];
#pragma unroll
    for (int a = 0; a < 2; a++)
#pragma unroll
      for (int b = 0; b < 8; b++) accB[a][b] = (f32x4){0.f, 0.f, 0.f, 0.f};
#pragma unroll
    for (int ks = 0; ks < 8; ks++) {
      s16x8 a0 = *(const s16x8*)&tbuf[l15 * LS_ + ks * 32 + l4 * 8];
      s16x8 a1 = *(const s16x8*)&tbuf[(16 + l15) * LS_ + ks * 32 + l4 * 8];
#pragma unroll
      for (int nt = 0; nt < 8; nt++) {
        s16x8 b = *(const s16x8*)(pbB + (size_t)nt * 16 * 256 + ks * 32);
        accB[0][nt] = MFMA16(a0, b, accB[0][nt]);
        accB[1][nt] = MFMA16(a1, b, accB[1][nt]);
      }
    }
    unsigned short* hout = hs + (size_t)t * (RT_ * CC_);
#pragma unroll
    for (int e = 0; e < 8; e++) {
      int mt = e >> 2, r = e & 3;
#pragma unroll
      for (int cc = 0; cc < 2; cc++) {
        float xi = accB[mt][cc * 4 + 0][r] + gb[cc][0];
        float xf = accB[mt][cc * 4 + 1][r] + gb[cc][1];
        float xg = accB[mt][cc * 4 + 2][r] + gb[cc][2];
        float xo = accB[mt][cc * 4 + 3][r] + gb[cc][3];
        float si = 1.f / (1.f + __expf(-xi));
        float sf = 1.f / (1.f + __expf(-xf));
        float so = 1.f / (1.f + __expf(-xo));
        float tg = 1.f - 2.f / (__expf(2.f * xg) + 1.f);
        int q = e * 2 + cc;
        float cn = sf * cr[q] + si * tg;
        cr[q] = cn;
        float th = 1.f - 2.f / (__expf(2.f * cn) + 1.f);
        unsigned short hv = f2bf(so * th);
        hbuf[hlds[e] + cc * 16] = hv;
        hout[hglb[e] + cc * 16] = hv;
      }
    }
    __syncthreads();   // h complete in LDS (drains vmcnt too)
    // post row 0 of h[t] to downstream neighbor (packed pairs, coalesced)
    if (doPost) {
      if (tid < 128) {
        unsigned v = ((unsigned*)hbuf)[tid];   // row 0 is contiguous at base
        __hip_atomic_store(mbox + ((size_t)(blk - 1) * WD_ + t) * 128 + tid, v,
                           __ATOMIC_RELAXED, __HIP_MEMORY_SCOPE_AGENT);
      }
      __syncthreads();   // drain posts (barrier implies vmcnt(0))
      if (tid == 0)
        __hip_atomic_store(upflag, (unsigned)(t + 1), __ATOMIC_RELAXED,
                           __HIP_MEMORY_SCOPE_AGENT);
    }
  }
}

// ---------------------------------------------------------------------------
// gather: out[b,o,hh,j] = hs0[hh+j][row][c0+hh] + (hh>0)*hs1[hh-1+63-j][row][c0+hh-1]
// ---------------------------------------------------------------------------
__global__ __launch_bounds__(256) void gather_kernel(
    const unsigned short* __restrict__ hs, float* __restrict__ out) {
  __shared__ unsigned short slab0[127 * 66 + 2];
  __shared__ unsigned short slab1[127 * 66 + 2];
  int blk = blockIdx.x;                    // bb*256 + o
  int bb = blk >> 8, o = blk & 255;
  int row = bb * 64 + (o >> 2);
  int c0 = (o & 3) * 64;
  int tid = threadIdx.x;
  for (int idx = tid; idx < 127 * 32; idx += 256) {
    int tt = idx >> 5, cu = idx & 31;
    unsigned v0 = *(const unsigned*)(hs + ((size_t)tt * RT_ + row) * 256 + c0 + cu * 2);
    unsigned v1 = *(const unsigned*)(hs + ((size_t)tt * RT_ + 1024 + row) * 256 + c0 + cu * 2);
    *(unsigned*)(slab0 + tt * 66 + cu * 2) = v0;
    *(unsigned*)(slab1 + tt * 66 + cu * 2) = v1;
  }
  __syncthreads();
  int j = tid & 63;
  int hh0 = (tid >> 6) * 16;
  float* ob = out + (size_t)blk * 4096;
  for (int hh = hh0; hh < hh0 + 16; hh++) {
    float v = bf2f(slab0[(hh + j) * 66 + hh]);
    if (hh > 0) v += bf2f(slab1[(hh - 1 + 63 - j) * 66 + (hh - 1)]);
    ob[hh * 64 + j] = v;
  }
}

// ---------------------------------------------------------------------------
extern "C" void kernel_launch(void* const* d_in, const int* in_sizes, int n_in,
                              void* d_out, int out_size, void* d_ws, size_t ws_size,
                              hipStream_t stream) {
  const float* x     = (const float*)d_in[0];
  const float* w_i2s = (const float*)d_in[1];
  const float* b_i2s = (const float*)d_in[2];
  const float* w_ih  = (const float*)d_in[3];
  const float* b_ih  = (const float*)d_in[4];
  const float* b_hh  = (const float*)d_in[5];
  const float* k0    = (const float*)d_in[6];
  const float* k1    = (const float*)d_in[7];
  const float* b_s2s = (const float*)d_in[8];
  float* out = (float*)d_out;

  char* ws = (char*)d_ws;
  // workspace map (bytes)
  float*          wm     = (float*)(ws + 0);                 //   256 KiB
  float*          cvec   = (float*)(ws + 262144);            //     1 KiB
  float*          gbias  = (float*)(ws + 263168);            //     4 KiB
  unsigned short* K01    = (unsigned short*)(ws + 267264);   //   256 KiB
  unsigned short* W2T    = (unsigned short*)(ws + 529408);   //   512 KiB
  unsigned*       flags  = (unsigned*)(ws + 1053696);        //     8 KiB
  unsigned*       mbox   = (unsigned*)(ws + 1061888);        // 4,161,536 B
  unsigned short* xs     = (unsigned short*)(ws + 5223424);  //    32 MiB
  unsigned short* hs     = (unsigned short*)(ws + 38777856); // 133,169,152 B
  const size_t NEEDED = 171947008;
  if (ws_size < NEEDED) return;

  hipMemsetAsync(flags, 0, 8192, stream);   // flags must start at 0
  prep_kernel<<<1797, 256, 0, stream>>>(w_i2s, b_i2s, w_ih, b_ih, b_hh, k0, k1,
                                        b_s2s, wm, K01, W2T, cvec, gbias);
  xs_kernel<<<1024, 256, 65536, stream>>>(x, wm, xs);
  lstm_persist<<<64, 512, 0, stream>>>(K01, W2T, xs, cvec, gbias, hs, mbox, flags);
  gather_kernel<<<4096, 256, 0, stream>>>(hs, out);
}